// Round 8
// baseline (316.568 us; speedup 1.0000x reference)
//
#include <hip/hip_runtime.h>
#include <hip/hip_bf16.h>

using bf16 = __bf16;
typedef __bf16 bf16x8 __attribute__((ext_vector_type(8)));
typedef float f32x4 __attribute__((ext_vector_type(4)));

__device__ __forceinline__ void gload_lds16(const bf16* g, bf16* l) {
  __builtin_amdgcn_global_load_lds(
      (const __attribute__((address_space(1))) void*)g,
      (__attribute__((address_space(3))) void*)l, 16, 0, 0);
}

// fp32 -> bf16, 8 elems/thread
__global__ __launch_bounds__(256) void cvt_f32_bf16(const float* __restrict__ in,
                                                    bf16* __restrict__ out, int n) {
  int i = (blockIdx.x * 256 + threadIdx.x) * 8;
  if (i >= n) return;
  float4 f0 = *(const float4*)&in[i];
  float4 f1 = *(const float4*)&in[i + 4];
  bf16x8 o;
  o[0] = (bf16)f0.x; o[1] = (bf16)f0.y; o[2] = (bf16)f0.z; o[3] = (bf16)f0.w;
  o[4] = (bf16)f1.x; o[5] = (bf16)f1.y; o[6] = (bf16)f1.z; o[7] = (bf16)f1.w;
  *(bf16x8*)&out[i] = o;
}

// C = A @ B^T. 256x256 tile, BK=64, 8 waves (2x4), wave out 128x64, acc[8][4].
// 2-buffer double-buffered LDS (128 KB), 4 phases/K-tile, 16 MFMA/phase.
// COMPILER-SCHEDULED phases: no sched_barrier, no manual lgkmcnt (the
// compiler emits precise lgkmcnt(N) for ds_read->MFMA deps and can overlap
// read-issue with MFMA drain across the phase boundary). Raw s_barrier pairs
// delimit phases; setprio(1) wraps MFMA clusters; counted vmcnt only.
// Stage slots (liveness-derived): P1(t): A1(t+1); P3(t): B0(t+2);
// P4(t): B1(t+2)+A0(t+2); vmcnt(6) at end of P4 certifies tile t+1
// (its last half-tile A1(t+1) was issued 3 phases earlier).
// Chunk swizzle c ^= (r&7) on stage-source and ds_read: 2 lanes/bank (free).
// EPI 0: bf16 C = scale*acc. EPI 1: bf16 C = exp(scale*acc).
// EPI 2: fp32 C = acc * Inv[row] + Add.
// Requires: M%256==0, N%256==0, K%64==0, K>=128; if gridDim.z>1, nwg%8==0.
template <int EPI>
__global__ __launch_bounds__(512, 2)
void gemm_bt(const bf16* __restrict__ A, const bf16* __restrict__ B,
             void* __restrict__ Cv, const float* __restrict__ Add,
             const float* __restrict__ Inv,
             int K, int lda, int ldb, int ldc,
             long sA, long sB, long sC, long sAdd, float scale) {
  int bx = blockIdx.x, by = blockIdx.y, bz = blockIdx.z;
  if (gridDim.z > 1) {  // XCD chunked swizzle
    const int gx = gridDim.x, gxy = gx * gridDim.y;
    const int nwg = gxy * gridDim.z;
    int lin = bx + gx * by + gxy * bz;
    lin = (lin & 7) * (nwg >> 3) + (lin >> 3);
    bz = lin / gxy; const int rem = lin - bz * gxy;
    by = rem / gx;  bx = rem - by * gx;
  }
  A += (long)bz * sA;
  B += (long)bz * sB;
  const int tid = threadIdx.x;
  const int lane = tid & 63;
  const int wave = tid >> 6;
  const int wr = wave >> 2;        // 0..1
  const int wc = wave & 3;         // 0..3
  const long brow = (long)bx * 256;
  const long bcol = (long)by * 256;

  __shared__ bf16 lds[65536];      // 128 KB

  f32x4 acc[8][4] = {};

  // staging: per half-tile (128 rows x 64 cols), 2 x 16B per thread.
  const int srow = tid >> 3;                       // 0..63
  const int scs  = (tid & 7) ^ (srow & 7);         // swizzled source chunk
  const bf16* gA = A + (brow + srow) * (long)lda + scs * 8;
  const bf16* gB = B + (bcol + srow) * (long)ldb + scs * 8;

  const int nk = K >> 6;

  auto stageA = [&](int t, int h) {
    bf16* dst = lds + (t & 1) * 32768 + h * 8192 + tid * 8;
    const bf16* g = gA + ((long)h * 128) * lda + (long)t * 64;
    gload_lds16(g, dst);
    gload_lds16(g + (long)64 * lda, dst + 4096);
  };
  auto stageB = [&](int t, int h) {
    bf16* dst = lds + (t & 1) * 32768 + 16384 + h * 8192 + tid * 8;
    const bf16* g = gB + ((long)h * 128) * ldb + (long)t * 64;
    gload_lds16(g, dst);
    gload_lds16(g + (long)64 * ldb, dst + 4096);
  };

  const int lk = lane >> 4;   // 0..3
  const int lr = lane & 15;   // row-within-frag

  auto rdA = [&](int d, int mi, int ks) -> bf16x8 {
    const int rt = wr * 128 + mi * 16 + lr;
    const int h = rt >> 7, r = rt & 127;
    const int c = (ks * 4 + lk) ^ (r & 7);
    return *(const bf16x8*)&lds[d * 32768 + h * 8192 + r * 64 + c * 8];
  };
  auto rdB = [&](int d, int ni, int ks) -> bf16x8 {
    const int rt = wc * 64 + ni * 16 + lr;
    const int h = rt >> 7, r = rt & 127;
    const int c = (ks * 4 + lk) ^ (r & 7);
    return *(const bf16x8*)&lds[d * 32768 + 16384 + h * 8192 + r * 64 + c * 8];
  };

  // prologue: tile 0 fully + B0(1),B1(1),A0(1); wait tile 0 (leave 6).
  stageA(0, 0); stageA(0, 1); stageB(0, 0); stageB(0, 1);
  if (nk > 1) {
    stageB(1, 0); stageB(1, 1); stageA(1, 0);
    asm volatile("s_waitcnt vmcnt(6)" ::: "memory");
  } else {
    asm volatile("s_waitcnt vmcnt(0)" ::: "memory");
  }
  __builtin_amdgcn_s_barrier();

  bf16x8 av[8][2], bv[4][2];

  for (int t = 0; t < nk; ++t) {
    const int d = t & 1;
    // ---- P1: quadrant (m-lo, n-lo). reads 12, stage A1(t+1)
#pragma unroll
    for (int mi = 0; mi < 4; ++mi) { av[mi][0] = rdA(d, mi, 0); av[mi][1] = rdA(d, mi, 1); }
#pragma unroll
    for (int ni = 0; ni < 2; ++ni) { bv[ni][0] = rdB(d, ni, 0); bv[ni][1] = rdB(d, ni, 1); }
    if (t + 1 < nk) stageA(t + 1, 1);
    __builtin_amdgcn_s_barrier();
    __builtin_amdgcn_s_setprio(1);
#pragma unroll
    for (int ks = 0; ks < 2; ++ks)
#pragma unroll
      for (int mi = 0; mi < 4; ++mi)
#pragma unroll
        for (int ni = 0; ni < 2; ++ni)
          acc[mi][ni] = __builtin_amdgcn_mfma_f32_16x16x32_bf16(av[mi][ks], bv[ni][ks], acc[mi][ni], 0, 0, 0);
    __builtin_amdgcn_s_setprio(0);
    __builtin_amdgcn_s_barrier();
    // ---- P2: quadrant (m-lo, n-hi). reads 4, no stage
#pragma unroll
    for (int ni = 2; ni < 4; ++ni) { bv[ni][0] = rdB(d, ni, 0); bv[ni][1] = rdB(d, ni, 1); }
    __builtin_amdgcn_s_barrier();
    __builtin_amdgcn_s_setprio(1);
#pragma unroll
    for (int ks = 0; ks < 2; ++ks)
#pragma unroll
      for (int mi = 0; mi < 4; ++mi)
#pragma unroll
        for (int ni = 2; ni < 4; ++ni)
          acc[mi][ni] = __builtin_amdgcn_mfma_f32_16x16x32_bf16(av[mi][ks], bv[ni][ks], acc[mi][ni], 0, 0, 0);
    __builtin_amdgcn_s_setprio(0);
    __builtin_amdgcn_s_barrier();
    // ---- P3: quadrant (m-hi, n-hi). reads 8, stage B0(t+2)
#pragma unroll
    for (int mi = 4; mi < 8; ++mi) { av[mi][0] = rdA(d, mi, 0); av[mi][1] = rdA(d, mi, 1); }
    if (t + 2 < nk) stageB(t + 2, 0);
    __builtin_amdgcn_s_barrier();
    __builtin_amdgcn_s_setprio(1);
#pragma unroll
    for (int ks = 0; ks < 2; ++ks)
#pragma unroll
      for (int mi = 4; mi < 8; ++mi)
#pragma unroll
        for (int ni = 2; ni < 4; ++ni)
          acc[mi][ni] = __builtin_amdgcn_mfma_f32_16x16x32_bf16(av[mi][ks], bv[ni][ks], acc[mi][ni], 0, 0, 0);
    __builtin_amdgcn_s_setprio(0);
    __builtin_amdgcn_s_barrier();
    // ---- P4: quadrant (m-hi, n-lo). stage B1(t+2)+A0(t+2), counted vmcnt
    if (t + 2 < nk) { stageB(t + 2, 1); stageA(t + 2, 0); }
    __builtin_amdgcn_s_barrier();
    __builtin_amdgcn_s_setprio(1);
#pragma unroll
    for (int ks = 0; ks < 2; ++ks)
#pragma unroll
      for (int mi = 4; mi < 8; ++mi)
#pragma unroll
        for (int ni = 0; ni < 2; ++ni)
          acc[mi][ni] = __builtin_amdgcn_mfma_f32_16x16x32_bf16(av[mi][ks], bv[ni][ks], acc[mi][ni], 0, 0, 0);
    __builtin_amdgcn_s_setprio(0);
    if (t + 2 < nk) { asm volatile("s_waitcnt vmcnt(6)" ::: "memory"); }
    else            { asm volatile("s_waitcnt vmcnt(0)" ::: "memory"); }
    __builtin_amdgcn_s_barrier();
  }

  // epilogue. C/D layout: col = lane&15, row = (lane>>4)*4 + j
  const int or0 = wr * 128 + ((lane >> 4) << 2);
  const int oc0 = wc * 64 + (lane & 15);
#pragma unroll
  for (int mi = 0; mi < 8; ++mi) {
#pragma unroll
    for (int ni = 0; ni < 4; ++ni) {
#pragma unroll
      for (int j = 0; j < 4; ++j) {
        const long row = brow + or0 + mi * 16 + j;
        const long col = bcol + oc0 + ni * 16;
        if constexpr (EPI == 0) {
          bf16* C = (bf16*)Cv + (long)bz * sC;
          C[row * ldc + col] = (bf16)(acc[mi][ni][j] * scale);
        } else if constexpr (EPI == 1) {
          bf16* C = (bf16*)Cv + (long)bz * sC;
          C[row * ldc + col] = (bf16)__expf(acc[mi][ni][j] * scale);
        } else {
          float* C = (float*)Cv + (long)bz * sC;
          const float* Ad = Add + (long)bz * sAdd;
          const float* iv = Inv + (long)bz * 2048;
          C[row * ldc + col] = acc[mi][ni][j] * iv[row] + Ad[row * ldc + col];
        }
      }
    }
  }
}

// per-row sum of exp-scores E (rows of 2048 bf16) -> inv[row] = 1/sum
__global__ __launch_bounds__(256) void rowsum_inv(const bf16* __restrict__ E,
                                                  float* __restrict__ inv) {
  const long row = blockIdx.x;
  const bf16* p = E + row * 2048;
  const int tid = threadIdx.x;
  bf16x8 v = *(const bf16x8*)&p[tid * 8];
  float s = 0.f;
#pragma unroll
  for (int i = 0; i < 8; ++i) s += (float)v[i];
#pragma unroll
  for (int off = 32; off > 0; off >>= 1) s += __shfl_xor(s, off, 64);
  __shared__ float red[4];
  if ((tid & 63) == 0) red[tid >> 6] = s;
  __syncthreads();
  if (tid == 0) inv[row] = 1.0f / (red[0] + red[1] + red[2] + red[3]);
}

extern "C" void kernel_launch(void* const* d_in, const int* in_sizes, int n_in,
                              void* d_out, int out_size, void* d_ws, size_t ws_size,
                              hipStream_t stream) {
  const float* q_in = (const float*)d_in[0];  // (8,2048,1024)
  const float* k_in = (const float*)d_in[1];  // (8,2048,1024)
  const float* Wq   = (const float*)d_in[2];  // (1024,1024)
  const float* Wk   = (const float*)d_in[3];
  const float* Wv   = (const float*)d_in[4];
  float* out = (float*)d_out;
  char* ws = (char*)d_ws;

  bf16* qb  = (bf16*)(ws);                 // 33,554,432 B
  bf16* kb  = (bf16*)(ws + 33554432);      // 33,554,432 B
  bf16* S   = (bf16*)(ws);                 // 67,108,864 B (reuse of qb+kb)
  bf16* Wqb = (bf16*)(ws + 67108864);
  float* inv = (float*)(ws + 67108864);    // 64 KB, reuses Wqb after proj Q
  bf16* Wkb = (bf16*)(ws + 69206016);
  bf16* Wvb = (bf16*)(ws + 71303168);
  bf16* Qp  = (bf16*)(ws + 73400320);
  bf16* Kp  = (bf16*)(ws + 106954752);
  bf16* Vpt = (bf16*)(ws + 140509184);     // (b,1024,2048) = Vp^T per batch

  cvt_f32_bf16<<<8192, 256, 0, stream>>>(q_in, qb, 16777216);
  cvt_f32_bf16<<<8192, 256, 0, stream>>>(k_in, kb, 16777216);
  cvt_f32_bf16<<<512, 256, 0, stream>>>(Wq, Wqb, 1048576);
  cvt_f32_bf16<<<512, 256, 0, stream>>>(Wk, Wkb, 1048576);
  cvt_f32_bf16<<<512, 256, 0, stream>>>(Wv, Wvb, 1048576);

  // Qp = qb @ Wq^T  (M=16384, N=1024, K=1024)
  gemm_bt<0><<<dim3(64, 4, 1), 512, 0, stream>>>(
      qb, Wqb, Qp, nullptr, nullptr, 1024, 1024, 1024, 1024, 0, 0, 0, 0, 1.0f);
  // Kp = kb @ Wk^T
  gemm_bt<0><<<dim3(64, 4, 1), 512, 0, stream>>>(
      kb, Wkb, Kp, nullptr, nullptr, 1024, 1024, 1024, 1024, 0, 0, 0, 0, 1.0f);
  // Vpt[b] = Wv @ qb[b]^T  (M=1024, N=2048, K=1024)
  gemm_bt<0><<<dim3(4, 8, 8), 512, 0, stream>>>(
      Wvb, qb, Vpt, nullptr, nullptr, 1024, 1024, 1024, 2048,
      0L, 2097152L, 2097152L, 0L, 1.0f);

  // S[b] = exp(Kp[b] @ Qp[b]^T / 32)  (M=2048, N=2048, K=1024) — max-free
  gemm_bt<1><<<dim3(8, 8, 8), 512, 0, stream>>>(
      Kp, Qp, S, nullptr, nullptr, 1024, 1024, 1024, 2048,
      2097152L, 2097152L, 4194304L, 0L, 0.03125f);

  // inv[row] = 1 / rowsum(S)
  rowsum_inv<<<16384, 256, 0, stream>>>(S, inv);

  // out[b] = (S[b] @ Vpt[b]') * inv + key_input[b]  (M=2048, N=1024, K=2048)
  gemm_bt<2><<<dim3(8, 4, 8), 512, 0, stream>>>(
      S, Vpt, out, k_in, inv, 2048, 2048, 2048, 1024,
      4194304L, 2097152L, 2097152L, 2097152L, 1.0f);
}

// Round 9
// 298.618 us; speedup vs baseline: 1.0601x; 1.0601x over previous
//
#include <hip/hip_runtime.h>
#include <hip/hip_bf16.h>

using bf16 = __bf16;
typedef __bf16 bf16x8 __attribute__((ext_vector_type(8)));
typedef float f32x4 __attribute__((ext_vector_type(4)));

__device__ __forceinline__ void gload_lds16(const bf16* g, bf16* l) {
  __builtin_amdgcn_global_load_lds(
      (const __attribute__((address_space(1))) void*)g,
      (__attribute__((address_space(3))) void*)l, 16, 0, 0);
}

// fp32 -> bf16, 8 elems/thread
__global__ __launch_bounds__(256) void cvt_f32_bf16(const float* __restrict__ in,
                                                    bf16* __restrict__ out, int n) {
  int i = (blockIdx.x * 256 + threadIdx.x) * 8;
  if (i >= n) return;
  float4 f0 = *(const float4*)&in[i];
  float4 f1 = *(const float4*)&in[i + 4];
  bf16x8 o;
  o[0] = (bf16)f0.x; o[1] = (bf16)f0.y; o[2] = (bf16)f0.z; o[3] = (bf16)f0.w;
  o[4] = (bf16)f1.x; o[5] = (bf16)f1.y; o[6] = (bf16)f1.z; o[7] = (bf16)f1.w;
  *(bf16x8*)&out[i] = o;
}

// transpose + cvt: out[c][r] = (bf16)in[r][c]. 64x64 tiles. R,C mult of 64.
__global__ __launch_bounds__(256) void tcvt_f32_bf16(const float* __restrict__ in,
                                                     bf16* __restrict__ out,
                                                     int R, int C) {
  __shared__ float tile[64][65];
  const int t = threadIdx.x;
  const int r0 = blockIdx.y * 64, c0 = blockIdx.x * 64;
  const int r = t >> 4, c4 = (t & 15) * 4;
#pragma unroll
  for (int rr = 0; rr < 64; rr += 16) {
    float4 v = *(const float4*)&in[(long)(r0 + r + rr) * C + c0 + c4];
    tile[r + rr][c4 + 0] = v.x; tile[r + rr][c4 + 1] = v.y;
    tile[r + rr][c4 + 2] = v.z; tile[r + rr][c4 + 3] = v.w;
  }
  __syncthreads();
  const int cc = t >> 2, rseg = (t & 3) * 16;
  bf16 tmp[16];
#pragma unroll
  for (int k = 0; k < 16; ++k) tmp[k] = (bf16)tile[rseg + k][cc];
  *(bf16x8*)&out[(long)(c0 + cc) * R + r0 + rseg] = *(bf16x8*)&tmp[0];
  *(bf16x8*)&out[(long)(c0 + cc) * R + r0 + rseg + 8] = *(bf16x8*)&tmp[8];
}

__global__ __launch_bounds__(256) void zero_f32(float* __restrict__ p, int n) {
  int i = (blockIdx.x * 256 + threadIdx.x) * 4;
  if (i < n) *(float4*)&p[i] = make_float4(0.f, 0.f, 0.f, 0.f);
}

// small split-K GEMM: C += A @ B^T over K-slice [z*256, z*256+256).
// 128x128 tile, 4 waves (2x2), BK=32, r1-verified structure, fp32 atomicAdd.
__global__ __launch_bounds__(256)
void gemm_small_atomic(const bf16* __restrict__ A, const bf16* __restrict__ B,
                       float* __restrict__ C, int lda, int ldb, int ldc) {
  const int tid = threadIdx.x;
  const int wave = tid >> 6;
  const int lane = tid & 63;
  const int wr = wave >> 1, wc = wave & 1;
  const long brow = (long)blockIdx.x * 128;
  const long bcol = (long)blockIdx.y * 128;
  const int kofs = blockIdx.z * 256;

  __shared__ bf16 As[128 * 32];
  __shared__ bf16 Bs[128 * 32];
  f32x4 acc[4][4] = {};

  const int r0 = tid >> 2;
  const int c0 = (tid & 3) * 8;
  const bf16* ga = A + (brow + r0) * (long)lda + kofs + c0;
  const bf16* gb = B + (bcol + r0) * (long)ldb + kofs + c0;
  bf16* la0 = As + tid * 8;
  bf16* la1 = As + 2048 + tid * 8;
  bf16* lb0 = Bs + tid * 8;
  bf16* lb1 = Bs + 2048 + tid * 8;
  const int afo = (wr * 64 + (lane & 15)) * 32 + (lane >> 4) * 8;
  const int bfo = (wc * 64 + (lane & 15)) * 32 + (lane >> 4) * 8;

  for (int kt = 0; kt < 8; ++kt) {
    gload_lds16(ga, la0);
    gload_lds16(ga + (long)64 * lda, la1);
    gload_lds16(gb, lb0);
    gload_lds16(gb + (long)64 * ldb, lb1);
    ga += 32; gb += 32;
    __syncthreads();
    bf16x8 av[4], bv[4];
#pragma unroll
    for (int i = 0; i < 4; ++i) {
      av[i] = *(const bf16x8*)&As[afo + i * 512];
      bv[i] = *(const bf16x8*)&Bs[bfo + i * 512];
    }
#pragma unroll
    for (int mi = 0; mi < 4; ++mi)
#pragma unroll
      for (int ni = 0; ni < 4; ++ni)
        acc[mi][ni] = __builtin_amdgcn_mfma_f32_16x16x32_bf16(av[mi], bv[ni],
                                                              acc[mi][ni], 0, 0, 0);
    __syncthreads();
  }

  const int or0 = wr * 64 + ((lane >> 4) << 2);
  const int oc0 = wc * 64 + (lane & 15);
#pragma unroll
  for (int mi = 0; mi < 4; ++mi)
#pragma unroll
    for (int ni = 0; ni < 4; ++ni)
#pragma unroll
      for (int j = 0; j < 4; ++j) {
        const long row = brow + or0 + mi * 16 + j;
        const long col = bcol + oc0 + ni * 16;
        atomicAdd(&C[row * ldc + col], acc[mi][ni][j]);
      }
}

// frags for one K-tile (BK=32): R[0..7]=A(mi), R[8..11]=B(ni). 12 x b128.
__device__ __forceinline__ void load_frags(const bf16* __restrict__ buf,
                                           int wr, int wc, int lk, int lr,
                                           bf16x8 (&R)[12]) {
#pragma unroll
  for (int mi = 0; mi < 8; ++mi) {
    const int r = wr * 128 + mi * 16 + lr;
    R[mi] = *(const bf16x8*)&buf[r * 32 + ((lk ^ ((r >> 1) & 3)) << 3)];
  }
#pragma unroll
  for (int ni = 0; ni < 4; ++ni) {
    const int r = wc * 64 + ni * 16 + lr;
    R[8 + ni] = *(const bf16x8*)&buf[8192 + r * 32 + ((lk ^ ((r >> 1) & 3)) << 3)];
  }
}

__device__ __forceinline__ void mfma_tile(const bf16x8 (&R)[12], f32x4 (&acc)[8][4]) {
  __builtin_amdgcn_s_setprio(1);
#pragma unroll
  for (int mi = 0; mi < 8; ++mi)
#pragma unroll
    for (int ni = 0; ni < 4; ++ni)
      acc[mi][ni] = __builtin_amdgcn_mfma_f32_16x16x32_bf16(R[mi], R[8 + ni], acc[mi][ni], 0, 0, 0);
  __builtin_amdgcn_s_setprio(0);
}

// C = A @ B^T. 256x256 tile, BK=32, 8 waves (2x4), wave out 128x64.
// K-split software pipeline (r6 structure — best measured).
// EPI 0: bf16 C = scale*acc. EPI 1: bf16 C = exp(scale*acc).
// EPI 2: fp32 C = acc * Inv[row] + (float)Add[row*ldc+col] (Add bf16).
// Requires: M%256==0, N%256==0, K%64==0, K>=256; if gridDim.z>1, nwg%8==0.
template <int EPI>
__global__ __launch_bounds__(512, 2)
void gemm_bt(const bf16* __restrict__ A, const bf16* __restrict__ B,
             void* __restrict__ Cv, const bf16* __restrict__ Add,
             const float* __restrict__ Inv,
             int K, int lda, int ldb, int ldc,
             long sA, long sB, long sC, long sAdd, float scale) {
  int bx = blockIdx.x, by = blockIdx.y, bz = blockIdx.z;
  if (gridDim.z > 1) {  // XCD chunked swizzle
    const int gx = gridDim.x, gxy = gx * gridDim.y;
    const int nwg = gxy * gridDim.z;
    int lin = bx + gx * by + gxy * bz;
    lin = (lin & 7) * (nwg >> 3) + (lin >> 3);
    bz = lin / gxy; const int rem = lin - bz * gxy;
    by = rem / gx;  bx = rem - by * gx;
  }
  A += (long)bz * sA;
  B += (long)bz * sB;
  const int tid = threadIdx.x;
  const int lane = tid & 63;
  const int wave = tid >> 6;
  const int wr = wave >> 2;
  const int wc = wave & 3;
  const long brow = (long)bx * 256;
  const long bcol = (long)by * 256;

  __shared__ bf16 lds[4][16384];

  f32x4 acc[8][4] = {};

  const int srow = tid >> 2;
  const int scg  = (tid & 3) ^ ((srow >> 1) & 3);
  const bf16* gA = A + (brow + srow) * (long)lda + scg * 8;
  const bf16* gB = B + (bcol + srow) * (long)ldb + scg * 8;
  const long a128 = (long)lda << 7;
  const long b128 = (long)ldb << 7;

  const int nk = K >> 5;

  auto stage = [&](int t) {
    bf16* buf = (bf16*)lds[t & 3];
    const bf16* a = gA + (long)t * 32;
    const bf16* b = gB + (long)t * 32;
    gload_lds16(a,        buf + tid * 8);
    gload_lds16(a + a128, buf + 4096 + tid * 8);
    gload_lds16(b,        buf + 8192 + tid * 8);
    gload_lds16(b + b128, buf + 12288 + tid * 8);
  };

  const int lk = lane >> 4;
  const int lr = lane & 15;

  stage(0); stage(1); stage(2);
  asm volatile("s_waitcnt vmcnt(4)" ::: "memory");
  __builtin_amdgcn_s_barrier();

  bf16x8 R0[12], R1[12];
  load_frags((const bf16*)lds[0], wr, wc, lk, lr, R0);

  for (int t = 0; t < nk; t += 2) {
    load_frags((const bf16*)lds[(t + 1) & 3], wr, wc, lk, lr, R1);
    if (t + 3 < nk) stage(t + 3);
    mfma_tile(R0, acc);
    if (t + 3 < nk) { asm volatile("s_waitcnt vmcnt(4)" ::: "memory"); }
    else            { asm volatile("s_waitcnt vmcnt(0)" ::: "memory"); }
    __builtin_amdgcn_s_barrier();
    if (t + 2 < nk) load_frags((const bf16*)lds[(t + 2) & 3], wr, wc, lk, lr, R0);
    if (t + 4 < nk) stage(t + 4);
    mfma_tile(R1, acc);
    if (t + 4 < nk) { asm volatile("s_waitcnt vmcnt(4)" ::: "memory"); }
    else            { asm volatile("s_waitcnt vmcnt(0)" ::: "memory"); }
    __builtin_amdgcn_s_barrier();
  }

  const int or0 = wr * 128 + ((lane >> 4) << 2);
  const int oc0 = wc * 64 + (lane & 15);
#pragma unroll
  for (int mi = 0; mi < 8; ++mi) {
#pragma unroll
    for (int ni = 0; ni < 4; ++ni) {
#pragma unroll
      for (int j = 0; j < 4; ++j) {
        const long row = brow + or0 + mi * 16 + j;
        const long col = bcol + oc0 + ni * 16;
        if constexpr (EPI == 0) {
          bf16* C = (bf16*)Cv + (long)bz * sC;
          C[row * ldc + col] = (bf16)(acc[mi][ni][j] * scale);
        } else if constexpr (EPI == 1) {
          bf16* C = (bf16*)Cv + (long)bz * sC;
          C[row * ldc + col] = (bf16)__expf(acc[mi][ni][j] * scale);
        } else {
          float* C = (float*)Cv + (long)bz * sC;
          const bf16* Ad = Add + (long)bz * sAdd;
          const float* iv = Inv + (long)bz * 2048;
          C[row * ldc + col] = acc[mi][ni][j] * iv[row] + (float)Ad[row * ldc + col];
        }
      }
    }
  }
}

// per-row sum of exp-scores E (rows of 2048 bf16) -> inv[row] = 1/sum
__global__ __launch_bounds__(256) void rowsum_inv(const bf16* __restrict__ E,
                                                  float* __restrict__ inv) {
  const long row = blockIdx.x;
  const bf16* p = E + row * 2048;
  const int tid = threadIdx.x;
  bf16x8 v = *(const bf16x8*)&p[tid * 8];
  float s = 0.f;
#pragma unroll
  for (int i = 0; i < 8; ++i) s += (float)v[i];
#pragma unroll
  for (int off = 32; off > 0; off >>= 1) s += __shfl_xor(s, off, 64);
  __shared__ float red[4];
  if ((tid & 63) == 0) red[tid >> 6] = s;
  __syncthreads();
  if (tid == 0) inv[row] = 1.0f / (red[0] + red[1] + red[2] + red[3]);
}

extern "C" void kernel_launch(void* const* d_in, const int* in_sizes, int n_in,
                              void* d_out, int out_size, void* d_ws, size_t ws_size,
                              hipStream_t stream) {
  const float* q_in = (const float*)d_in[0];  // (8,2048,1024)
  const float* k_in = (const float*)d_in[1];  // (8,2048,1024)
  const float* Wq   = (const float*)d_in[2];  // (1024,1024)
  const float* Wk   = (const float*)d_in[3];
  const float* Wv   = (const float*)d_in[4];
  float* out = (float*)d_out;
  char* ws = (char*)d_ws;

  // layout (peak 174,063,616 B — same proven footprint as rounds 1-8):
  bf16*  qb   = (bf16*)(ws);                  // 0   .. 32 MB
  bf16*  kb   = (bf16*)(ws + 33554432);       // 32  .. 64 MB
  bf16*  S    = (bf16*)(ws + 67108864);       // 64  .. 128 MB (written AFTER GT* dead)
  float* GTf  = (float*)(ws + 67108864);      // overlay S: 4 MB, dead before S write
  bf16*  GTb  = (bf16*)(ws + 71303168);       // overlay S: 2 MB, dead before S write
  bf16*  T1   = (bf16*)(ws + 134217728);      // 128 .. 160 MB
  bf16*  Vpt  = (bf16*)(ws + 134217728);      // reuses T1 slot (T1 dead after scores)
  bf16*  Wvb  = (bf16*)(ws + 167772160);      // 2 MB
  bf16*  WqTb = (bf16*)(ws + 169869312);      // 2 MB
  bf16*  WkTb = (bf16*)(ws + 171966464);      // 2 MB
  float* inv  = (float*)(ws + 169869312);     // overlay WqTb (dead after GT GEMM)

  // 1) conversions / transposes / zero
  zero_f32<<<1024, 256, 0, stream>>>(GTf, 1048576);
  tcvt_f32_bf16<<<dim3(16, 16), 256, 0, stream>>>(Wq, WqTb, 1024, 1024);
  tcvt_f32_bf16<<<dim3(16, 16), 256, 0, stream>>>(Wk, WkTb, 1024, 1024);
  cvt_f32_bf16<<<8192, 256, 0, stream>>>(q_in, qb, 16777216);
  cvt_f32_bf16<<<8192, 256, 0, stream>>>(k_in, kb, 16777216);
  cvt_f32_bf16<<<512, 256, 0, stream>>>(Wv, Wvb, 1048576);

  // 2) GT = Wq^T @ Wk  (1024x1024, K=1024 split 4x256, fp32 atomic) -> bf16
  gemm_small_atomic<<<dim3(8, 8, 4), 256, 0, stream>>>(WqTb, WkTb, GTf, 1024, 1024, 1024);
  cvt_f32_bf16<<<512, 256, 0, stream>>>(GTf, GTb, 1048576);

  // 3) T1 = kb @ GT^T = kb @ (Wk^T Wq)   (M=16384, N=1024, K=1024)
  gemm_bt<0><<<dim3(64, 4, 1), 512, 0, stream>>>(
      kb, GTb, T1, nullptr, nullptr, 1024, 1024, 1024, 1024, 0, 0, 0, 0, 1.0f);

  // 4) S[b] = exp(T1[b] @ qb[b]^T / 32)  == exp(Kp Qp^T / 32)
  gemm_bt<1><<<dim3(8, 8, 8), 512, 0, stream>>>(
      T1, qb, S, nullptr, nullptr, 1024, 1024, 1024, 2048,
      2097152L, 2097152L, 4194304L, 0L, 0.03125f);

  // 5) Vpt[b] = Wv @ qb[b]^T  (M=1024, N=2048, K=1024) — into T1's slot
  gemm_bt<0><<<dim3(4, 8, 8), 512, 0, stream>>>(
      Wvb, qb, Vpt, nullptr, nullptr, 1024, 1024, 1024, 2048,
      0L, 2097152L, 2097152L, 0L, 1.0f);

  // 6) inv[row] = 1 / rowsum(S)
  rowsum_inv<<<16384, 256, 0, stream>>>(S, inv);

  // 7) out[b] = (S[b] @ Vpt[b]') * inv + kb[b]  (M=2048, N=1024, K=2048)
  gemm_bt<2><<<dim3(8, 4, 8), 512, 0, stream>>>(
      S, Vpt, out, kb, inv, 2048, 2048, 2048, 1024,
      4194304L, 2097152L, 2097152L, 2097152L, 1.0f);
}